// Round 4
// baseline (2288.694 us; speedup 1.0000x reference)
//
#include <hip/hip_runtime.h>
#include <hip/hip_bf16.h>

#define D_DIM 3072
#define NTRAIN 16384
#define NTEST 8192

typedef __attribute__((ext_vector_type(8))) short short8;
typedef __attribute__((ext_vector_type(4))) float f32x4;

__device__ __forceinline__ unsigned short f2bf(float f) {
  union { float f; unsigned u; } x; x.f = f;
  unsigned r = x.u + 0x7FFFu + ((x.u >> 16) & 1u);
  return (unsigned short)(r >> 16);
}

__device__ __forceinline__ void gload16(const unsigned short* g, unsigned short* l) {
  __builtin_amdgcn_global_load_lds(
      (__attribute__((address_space(1))) void*)g,
      (__attribute__((address_space(3))) void*)l, 16, 0, 0);
}

// ---------------- pass 0: converts / transpose / copy ----------------
__global__ void k_convert(const float* __restrict__ in, unsigned short* __restrict__ out, long n4) {
  long i = (long)blockIdx.x * blockDim.x + threadIdx.x;
  long stride = (long)gridDim.x * blockDim.x;
  for (; i < n4; i += stride) {
    float4 v = reinterpret_cast<const float4*>(in)[i];
    ushort4 o;
    o.x = f2bf(v.x); o.y = f2bf(v.y); o.z = f2bf(v.z); o.w = f2bf(v.w);
    reinterpret_cast<ushort4*>(out)[i] = o;
  }
}

__global__ void k_copy4(const float4* __restrict__ in, float4* __restrict__ out, long n4) {
  long i = (long)blockIdx.x * blockDim.x + threadIdx.x;
  long stride = (long)gridDim.x * blockDim.x;
  for (; i < n4; i += stride) out[i] = in[i];
}

// Mt[n][k] = bf16(M[k][n])
__global__ void k_transpose_bf16(const float* __restrict__ M, unsigned short* __restrict__ Mt) {
  __shared__ float t[32][33];
  int bx = blockIdx.x * 32, by = blockIdx.y * 32;
  int tx = threadIdx.x, ty = threadIdx.y;  // 32 x 8
#pragma unroll
  for (int i = 0; i < 32; i += 8)
    t[ty + i][tx] = M[(size_t)(by + ty + i) * D_DIM + bx + tx];
  __syncthreads();
#pragma unroll
  for (int i = 0; i < 32; i += 8)
    Mt[(size_t)(bx + ty + i) * D_DIM + by + tx] = f2bf(t[tx][ty + i]);
}

// ---------------- shared 128x128 BT main loop, T2 XOR-swizzled LDS ----------------
__device__ __forceinline__ void mainloop(const unsigned short* __restrict__ A,
                                         const unsigned short* __restrict__ B,
                                         int K, int rowBase, int colBase,
                                         unsigned short* As, unsigned short* Bs,
                                         f32x4 acc[4][4]) {
  const int tid = threadIdx.x;
  const int lane = tid & 63;
  const int wm = (tid >> 6) >> 1, wn = (tid >> 6) & 1;
  const int sr = tid >> 3;                       // staging row 0..31 (+c*32)
  const int ssl = tid & 7;                       // physical 16B slot
  const int scol = ((ssl ^ (sr & 7)) * 8);       // pre-swizzled global column
  const unsigned short* ga = A + (size_t)(rowBase + sr) * K + scol;
  const unsigned short* gb = B + (size_t)(colBase + sr) * K + scol;
  const int arow = wm * 64 + (lane & 15);
  const int brow = wn * 64 + (lane & 15);
  const int lsw = lane & 7;                      // row&7 for this lane's rows
  const int lhi = lane >> 4;                     // 0..3
  for (int k0 = 0; k0 < K; k0 += 64) {
#pragma unroll
    for (int c = 0; c < 4; ++c) {
      gload16(ga + (size_t)c * 32 * K + k0, As + c * 2048 + tid * 8);
      gload16(gb + (size_t)c * 32 * K + k0, Bs + c * 2048 + tid * 8);
    }
    __syncthreads();
#pragma unroll
    for (int kk = 0; kk < 2; ++kk) {
      short8 af[4], bfr[4];
      const int sl = ((lhi + kk * 4) ^ lsw) * 8;  // swizzled read slot
#pragma unroll
      for (int i = 0; i < 4; ++i) {
        af[i]  = *reinterpret_cast<const short8*>(&As[(arow + i * 16) * 64 + sl]);
        bfr[i] = *reinterpret_cast<const short8*>(&Bs[(brow + i * 16) * 64 + sl]);
      }
#pragma unroll
      for (int i = 0; i < 4; ++i)
#pragma unroll
        for (int j = 0; j < 4; ++j)
          acc[i][j] = __builtin_amdgcn_mfma_f32_16x16x32_bf16(af[i], bfr[j], acc[i][j], 0, 0, 0);
    }
    __syncthreads();
  }
}

// ---------------- GEMM1: X @ M  (B = Mt). Epilogue: norm2 (+ optional sM write) ----
template <bool WRITE_SM>
__global__ __launch_bounds__(256, 3) void k_gemm_xm(const unsigned short* __restrict__ A,
                                                    const unsigned short* __restrict__ Bt,
                                                    const float* __restrict__ Xf,
                                                    unsigned short* __restrict__ smOut,
                                                    float* __restrict__ norm) {
  __shared__ unsigned short As[128 * 64], Bs[128 * 64];
  const int rowBase = blockIdx.y * 128, colBase = blockIdx.x * 128;
  f32x4 acc[4][4] = {};
  mainloop(A, Bt, D_DIM, rowBase, colBase, As, Bs, acc);
  const int tid = threadIdx.x, lane = tid & 63;
  const int wm = (tid >> 6) >> 1, wn = (tid >> 6) & 1;
  const int r0 = wm * 64 + (lane >> 4) * 4;
  const int c0 = colBase + wn * 64 + (lane & 15);
#pragma unroll
  for (int mi = 0; mi < 4; ++mi) {
#pragma unroll
    for (int r = 0; r < 4; ++r) {
      const size_t grow = rowBase + r0 + mi * 16 + r;
      float v = 0.f;
#pragma unroll
      for (int ni = 0; ni < 4; ++ni) {
        float a = acc[mi][ni][r];
        int gcol = c0 + ni * 16;
        v += a * Xf[grow * D_DIM + gcol];
        if (WRITE_SM) smOut[grow * D_DIM + gcol] = f2bf(a);
      }
      v += __shfl_xor(v, 1); v += __shfl_xor(v, 2);
      v += __shfl_xor(v, 4); v += __shfl_xor(v, 8);
      if ((lane & 15) == 0) atomicAdd(&norm[grow], v);
    }
  }
}

// ---------------- GEMM2: sM @ x_test^T with fused K + column-partial reduction ----
// Two-pass epilogue to stay spill-free under the 3-waves/SIMD budget:
//   pass 1: acc <- exp2(-log2e/gamma * sqrt(sn + cn - 2*acc))  (in place, ~3 temps)
//   pass 2: acc-streaming y-weighted reduction (ps[11] + y only; frags dead)
__global__ __launch_bounds__(256, 3) void k_gemm_cross(const unsigned short* __restrict__ sM,
                                                       const unsigned short* __restrict__ Xt16,
                                                       const float* __restrict__ Y,
                                                       const float* __restrict__ sn2,
                                                       const float* __restrict__ cn2,
                                                       float* __restrict__ part) {
  __shared__ unsigned short As[128 * 64], Bs[128 * 64];
  const int tid = threadIdx.x;
  const int rowBase = blockIdx.y * 128, colBase = blockIdx.x * 128;
  f32x4 acc[4][4] = {};
  mainloop(sM, Xt16, D_DIM, rowBase, colBase, As, Bs, acc);
  float* ylds = reinterpret_cast<float*>(As);                   // [128][12] padded
  float* snlds = ylds + 128 * 12;                               // [128]
  float (*pcol)[11] = reinterpret_cast<float(*)[11]>(Bs);       // [128][11]
  for (int i = tid; i < 1280; i += 256)
    ylds[(i / 10) * 12 + (i % 10)] = Y[(size_t)rowBase * 10 + i];
  for (int i = tid; i < 128; i += 256) snlds[i] = sn2[rowBase + i];
  for (int i = tid; i < 128 * 11; i += 256) (&pcol[0][0])[i] = 0.f;
  __syncthreads();
  const int lane = tid & 63;
  const int wm = (tid >> 6) >> 1, wn = (tid >> 6) & 1;
  const int r0 = wm * 64 + (lane >> 4) * 4;
  const int c0l = wn * 64 + (lane & 15);

  // ---- pass 1: in-place transform acc -> kv ----
  float cn[4];
#pragma unroll
  for (int ni = 0; ni < 4; ++ni) cn[ni] = cn2[colBase + c0l + ni * 16];
#pragma unroll
  for (int mi = 0; mi < 4; ++mi) {
#pragma unroll
    for (int r = 0; r < 4; ++r) {
      const float sn = snlds[r0 + mi * 16 + r];
#pragma unroll
      for (int ni = 0; ni < 4; ++ni) {
        float d2 = sn + cn[ni] - 2.f * acc[mi][ni][r];
        acc[mi][ni][r] = exp2f(-0.14426950408889634f * sqrtf(fmaxf(d2, 0.f)));
      }
    }
  }

  // ---- pass 2: y-weighted column reduction ----
#pragma unroll
  for (int ni = 0; ni < 4; ++ni) {
    float ps[11];
#pragma unroll
    for (int c = 0; c < 11; ++c) ps[c] = 0.f;
#pragma unroll
    for (int mi = 0; mi < 4; ++mi) {
#pragma unroll
      for (int r = 0; r < 4; ++r) {
        const int lrow = r0 + mi * 16 + r;
        const float kv = acc[mi][ni][r];
        ps[10] += kv;
        f32x4 y0 = *reinterpret_cast<const f32x4*>(&ylds[lrow * 12]);
        f32x4 y1 = *reinterpret_cast<const f32x4*>(&ylds[lrow * 12 + 4]);
        float2 y2 = *reinterpret_cast<const float2*>(&ylds[lrow * 12 + 8]);
#pragma unroll
        for (int c = 0; c < 4; ++c) ps[c] += kv * y0[c];
#pragma unroll
        for (int c = 0; c < 4; ++c) ps[4 + c] += kv * y1[c];
        ps[8] += kv * y2.x;
        ps[9] += kv * y2.y;
      }
    }
#pragma unroll
    for (int c = 0; c < 11; ++c) {
      float v = ps[c];
      v += __shfl_xor(v, 16);
      v += __shfl_xor(v, 32);
      if (lane < 16) atomicAdd(&pcol[wn * 64 + ni * 16 + lane][c], v);
    }
  }
  __syncthreads();
  if (tid < 128) {
    int gcol = colBase + tid;
#pragma unroll
    for (int c = 0; c < 11; ++c)
      part[((size_t)blockIdx.y * 11 + c) * NTEST + gcol] = pcol[tid][c];
  }
}

// ---------------- final reduce: out[t,c] = num/den ----------------
__global__ void k_reduce(const float* __restrict__ part, float* __restrict__ out) {
  int t = blockIdx.x * blockDim.x + threadIdx.x;  // 8192 threads
  float num[10] = {0, 0, 0, 0, 0, 0, 0, 0, 0, 0};
  float den = 0.f;
  for (int it = 0; it < NTRAIN / 128; ++it) {
    const float* p = part + (size_t)it * 11 * NTEST + t;
#pragma unroll
    for (int c = 0; c < 10; ++c) num[c] += p[(size_t)c * NTEST];
    den += p[(size_t)10 * NTEST];
  }
  float inv = 1.f / den;
#pragma unroll
  for (int c = 0; c < 10; ++c) out[(size_t)t * 10 + c] = num[c] * inv;
}

extern "C" void kernel_launch(void* const* d_in, const int* in_sizes, int n_in,
                              void* d_out, int out_size, void* d_ws, size_t ws_size,
                              hipStream_t stream) {
  const float* x_train = (const float*)d_in[0];
  const float* y_train = (const float*)d_in[1];
  const float* x_test  = (const float*)d_in[2];
  const float* M       = (const float*)d_in[3];
  float* out = (float*)d_out;

  char* ws = (char*)d_ws;
  unsigned short* xtr16 = (unsigned short*)(ws + 0);          // 16384*3072*2 = 100663296
  unsigned short* xte16 = (unsigned short*)(ws + 100663296);  // 8192*3072*2  = 50331648
  unsigned short* Mt16  = (unsigned short*)(ws + 150994944);  // 3072*3072*2  = 18874368
  unsigned short* sM16  = (unsigned short*)(ws + 169869312);  // 16384*3072*2 = 100663296
  float* s_n2 = (float*)(ws + 270532608);                     // 65536
  float* c_n2 = (float*)(ws + 270598144);                     // 32768
  float* part = (float*)(ws + 270630912);                     // 128*11*8192*4 = 46137344

  hipMemsetAsync(ws + 270532608, 0, 98304, stream);  // s_n2 + c_n2

  k_convert<<<2048, 256, 0, stream>>>(x_train, xtr16, (long)NTRAIN * D_DIM / 4);
  k_convert<<<2048, 256, 0, stream>>>(x_test, xte16, (long)NTEST * D_DIM / 4);
  k_transpose_bf16<<<dim3(96, 96), dim3(32, 8), 0, stream>>>(M, Mt16);
  k_copy4<<<2048, 256, 0, stream>>>((const float4*)M, (float4*)(out + 81920),
                                    (long)D_DIM * D_DIM / 4);

  k_gemm_xm<true><<<dim3(24, 128), 256, 0, stream>>>(xtr16, Mt16, x_train, sM16, s_n2);
  k_gemm_xm<false><<<dim3(24, 64), 256, 0, stream>>>(xte16, Mt16, x_test, nullptr, c_n2);

  k_gemm_cross<<<dim3(64, 128), 256, 0, stream>>>(sM16, xte16, y_train, s_n2, c_n2, part);
  k_reduce<<<32, 256, 0, stream>>>(part, out);
}

// Round 5
// 1866.439 us; speedup vs baseline: 1.2262x; 1.2262x over previous
//
#include <hip/hip_runtime.h>
#include <hip/hip_bf16.h>

#define D_DIM 3072
#define NTRAIN 16384
#define NTEST 8192

typedef __attribute__((ext_vector_type(8))) short short8;
typedef __attribute__((ext_vector_type(4))) float f32x4;

__device__ __forceinline__ unsigned short f2bf(float f) {
  union { float f; unsigned u; } x; x.f = f;
  unsigned r = x.u + 0x7FFFu + ((x.u >> 16) & 1u);
  return (unsigned short)(r >> 16);
}

__device__ __forceinline__ void gload16(const unsigned short* g, unsigned short* l) {
  __builtin_amdgcn_global_load_lds(
      (__attribute__((address_space(1))) void*)g,
      (__attribute__((address_space(3))) void*)l, 16, 0, 0);
}

// ---------------- pass 0: converts / transpose / copy ----------------
__global__ void k_convert(const float* __restrict__ in, unsigned short* __restrict__ out, long n4) {
  long i = (long)blockIdx.x * blockDim.x + threadIdx.x;
  long stride = (long)gridDim.x * blockDim.x;
  for (; i < n4; i += stride) {
    float4 v = reinterpret_cast<const float4*>(in)[i];
    ushort4 o;
    o.x = f2bf(v.x); o.y = f2bf(v.y); o.z = f2bf(v.z); o.w = f2bf(v.w);
    reinterpret_cast<ushort4*>(out)[i] = o;
  }
}

__global__ void k_copy4(const float4* __restrict__ in, float4* __restrict__ out, long n4) {
  long i = (long)blockIdx.x * blockDim.x + threadIdx.x;
  long stride = (long)gridDim.x * blockDim.x;
  for (; i < n4; i += stride) out[i] = in[i];
}

// Mt[n][k] = bf16(M[k][n])
__global__ void k_transpose_bf16(const float* __restrict__ M, unsigned short* __restrict__ Mt) {
  __shared__ float t[32][33];
  int bx = blockIdx.x * 32, by = blockIdx.y * 32;
  int tx = threadIdx.x, ty = threadIdx.y;  // 32 x 8
#pragma unroll
  for (int i = 0; i < 32; i += 8)
    t[ty + i][tx] = M[(size_t)(by + ty + i) * D_DIM + bx + tx];
  __syncthreads();
#pragma unroll
  for (int i = 0; i < 32; i += 8)
    Mt[(size_t)(bx + ty + i) * D_DIM + by + tx] = f2bf(t[tx][ty + i]);
}

// ------- 128x128 BT main loop, 512 threads (8 waves, 4M x 2N), T2 swizzle -------
// Per wave: 32(M) x 64(N) output -> acc[2][4] (32 regs). Frags 24 regs.
// Spill-free at __launch_bounds__(512,4): 4 waves/SIMD, budget 128 regs/thread.
__device__ __forceinline__ void mainloop512(const unsigned short* __restrict__ A,
                                            const unsigned short* __restrict__ B,
                                            int K, int rowBase, int colBase,
                                            unsigned short* As, unsigned short* Bs,
                                            f32x4 acc[2][4]) {
  const int tid = threadIdx.x;
  const int lane = tid & 63;
  const int wave = tid >> 6;                     // 0..7
  const int wm = wave >> 1, wn = wave & 1;       // 4M x 2N
  const int sr = tid >> 3;                       // staging row 0..63 (+c*64)
  const int ssl = tid & 7;                       // physical 16B slot
  const int scol = ((ssl ^ (sr & 7)) * 8);       // pre-swizzled global column
  const unsigned short* ga = A + (size_t)(rowBase + sr) * K + scol;
  const unsigned short* gb = B + (size_t)(colBase + sr) * K + scol;
  const int arow = wm * 32 + (lane & 15);
  const int brow = wn * 64 + (lane & 15);
  const int lsw = lane & 7;
  const int lhi = lane >> 4;
  for (int k0 = 0; k0 < K; k0 += 64) {
#pragma unroll
    for (int c = 0; c < 2; ++c) {
      gload16(ga + (size_t)c * 64 * K + k0, As + c * 4096 + tid * 8);
      gload16(gb + (size_t)c * 64 * K + k0, Bs + c * 4096 + tid * 8);
    }
    __syncthreads();
#pragma unroll
    for (int kk = 0; kk < 2; ++kk) {
      short8 af[2], bfr[4];
      const int sl = ((lhi + kk * 4) ^ lsw) * 8;  // swizzled read slot
#pragma unroll
      for (int i = 0; i < 2; ++i)
        af[i] = *reinterpret_cast<const short8*>(&As[(arow + i * 16) * 64 + sl]);
#pragma unroll
      for (int j = 0; j < 4; ++j)
        bfr[j] = *reinterpret_cast<const short8*>(&Bs[(brow + j * 16) * 64 + sl]);
#pragma unroll
      for (int i = 0; i < 2; ++i)
#pragma unroll
        for (int j = 0; j < 4; ++j)
          acc[i][j] = __builtin_amdgcn_mfma_f32_16x16x32_bf16(af[i], bfr[j], acc[i][j], 0, 0, 0);
    }
    __syncthreads();
  }
}

// ---------------- GEMM1: X @ M  (B = Mt). Epilogue: norm2 (+ optional sM write) ----
template <bool WRITE_SM>
__global__ __launch_bounds__(512, 4) void k_gemm_xm(const unsigned short* __restrict__ A,
                                                    const unsigned short* __restrict__ Bt,
                                                    const float* __restrict__ Xf,
                                                    unsigned short* __restrict__ smOut,
                                                    float* __restrict__ norm) {
  __shared__ unsigned short As[128 * 64], Bs[128 * 64];
  const int rowBase = blockIdx.y * 128, colBase = blockIdx.x * 128;
  f32x4 acc[2][4] = {};
  mainloop512(A, Bt, D_DIM, rowBase, colBase, As, Bs, acc);
  const int tid = threadIdx.x, lane = tid & 63;
  const int wave = tid >> 6;
  const int wm = wave >> 1, wn = wave & 1;
  const int r0 = wm * 32 + (lane >> 4) * 4;
  const int c0 = colBase + wn * 64 + (lane & 15);
#pragma unroll
  for (int mi = 0; mi < 2; ++mi) {
#pragma unroll
    for (int r = 0; r < 4; ++r) {
      const size_t grow = rowBase + r0 + mi * 16 + r;
      float v = 0.f;
#pragma unroll
      for (int ni = 0; ni < 4; ++ni) {
        float a = acc[mi][ni][r];
        int gcol = c0 + ni * 16;
        v += a * Xf[grow * D_DIM + gcol];
        if (WRITE_SM) smOut[grow * D_DIM + gcol] = f2bf(a);
      }
      v += __shfl_xor(v, 1); v += __shfl_xor(v, 2);
      v += __shfl_xor(v, 4); v += __shfl_xor(v, 8);
      if ((lane & 15) == 0) atomicAdd(&norm[grow], v);
    }
  }
}

// ---------------- GEMM2: sM @ x_test^T, fused K + column-partial reduction ----
__global__ __launch_bounds__(512, 4) void k_gemm_cross(const unsigned short* __restrict__ sM,
                                                       const unsigned short* __restrict__ Xt16,
                                                       const float* __restrict__ Y,
                                                       const float* __restrict__ sn2,
                                                       const float* __restrict__ cn2,
                                                       float* __restrict__ part) {
  __shared__ unsigned short As[128 * 64], Bs[128 * 64];
  const int tid = threadIdx.x;
  const int rowBase = blockIdx.y * 128, colBase = blockIdx.x * 128;
  f32x4 acc[2][4] = {};
  mainloop512(sM, Xt16, D_DIM, rowBase, colBase, As, Bs, acc);
  float* ylds = reinterpret_cast<float*>(As);                   // [128][12] padded
  float* snlds = ylds + 128 * 12;                               // [128]
  float (*pcol)[11] = reinterpret_cast<float(*)[11]>(Bs);       // [128][11]
  for (int i = tid; i < 1280; i += 512)
    ylds[(i / 10) * 12 + (i % 10)] = Y[(size_t)rowBase * 10 + i];
  if (tid < 128) snlds[tid] = sn2[rowBase + tid];
  for (int i = tid; i < 128 * 11; i += 512) (&pcol[0][0])[i] = 0.f;
  __syncthreads();
  const int lane = tid & 63;
  const int wave = tid >> 6;
  const int wm = wave >> 1, wn = wave & 1;
  const int r0 = wm * 32 + (lane >> 4) * 4;
  const int c0l = wn * 64 + (lane & 15);
#pragma unroll
  for (int ni = 0; ni < 4; ++ni) {
    const float cnv = cn2[colBase + c0l + ni * 16];
    float ps[11];
#pragma unroll
    for (int c = 0; c < 11; ++c) ps[c] = 0.f;
#pragma unroll
    for (int mi = 0; mi < 2; ++mi) {
#pragma unroll
      for (int r = 0; r < 4; ++r) {
        const int lrow = r0 + mi * 16 + r;
        float d2 = snlds[lrow] + cnv - 2.f * acc[mi][ni][r];
        float kv = exp2f(-0.14426950408889634f * sqrtf(fmaxf(d2, 0.f)));
        ps[10] += kv;
        f32x4 y0 = *reinterpret_cast<const f32x4*>(&ylds[lrow * 12]);
        f32x4 y1 = *reinterpret_cast<const f32x4*>(&ylds[lrow * 12 + 4]);
        float2 y2 = *reinterpret_cast<const float2*>(&ylds[lrow * 12 + 8]);
#pragma unroll
        for (int c = 0; c < 4; ++c) ps[c] += kv * y0[c];
#pragma unroll
        for (int c = 0; c < 4; ++c) ps[4 + c] += kv * y1[c];
        ps[8] += kv * y2.x;
        ps[9] += kv * y2.y;
      }
    }
#pragma unroll
    for (int c = 0; c < 11; ++c) {
      float v = ps[c];
      v += __shfl_xor(v, 16);
      v += __shfl_xor(v, 32);
      if (lane < 16) atomicAdd(&pcol[wn * 64 + ni * 16 + lane][c], v);
    }
  }
  __syncthreads();
  if (tid < 128) {
    int gcol = colBase + tid;
#pragma unroll
    for (int c = 0; c < 11; ++c)
      part[((size_t)blockIdx.y * 11 + c) * NTEST + gcol] = pcol[tid][c];
  }
}

// ---------------- final reduce: out[t,c] = num/den ----------------
__global__ void k_reduce(const float* __restrict__ part, float* __restrict__ out) {
  int t = blockIdx.x * blockDim.x + threadIdx.x;  // 8192 threads
  float num[10] = {0, 0, 0, 0, 0, 0, 0, 0, 0, 0};
  float den = 0.f;
  for (int it = 0; it < NTRAIN / 128; ++it) {
    const float* p = part + (size_t)it * 11 * NTEST + t;
#pragma unroll
    for (int c = 0; c < 10; ++c) num[c] += p[(size_t)c * NTEST];
    den += p[(size_t)10 * NTEST];
  }
  float inv = 1.f / den;
#pragma unroll
  for (int c = 0; c < 10; ++c) out[(size_t)t * 10 + c] = num[c] * inv;
}

extern "C" void kernel_launch(void* const* d_in, const int* in_sizes, int n_in,
                              void* d_out, int out_size, void* d_ws, size_t ws_size,
                              hipStream_t stream) {
  const float* x_train = (const float*)d_in[0];
  const float* y_train = (const float*)d_in[1];
  const float* x_test  = (const float*)d_in[2];
  const float* M       = (const float*)d_in[3];
  float* out = (float*)d_out;

  char* ws = (char*)d_ws;
  unsigned short* xtr16 = (unsigned short*)(ws + 0);          // 16384*3072*2 = 100663296
  unsigned short* xte16 = (unsigned short*)(ws + 100663296);  // 8192*3072*2  = 50331648
  unsigned short* Mt16  = (unsigned short*)(ws + 150994944);  // 3072*3072*2  = 18874368
  unsigned short* sM16  = (unsigned short*)(ws + 169869312);  // 16384*3072*2 = 100663296
  float* s_n2 = (float*)(ws + 270532608);                     // 65536
  float* c_n2 = (float*)(ws + 270598144);                     // 32768
  float* part = (float*)(ws + 270630912);                     // 128*11*8192*4 = 46137344

  hipMemsetAsync(ws + 270532608, 0, 98304, stream);  // s_n2 + c_n2

  k_convert<<<2048, 256, 0, stream>>>(x_train, xtr16, (long)NTRAIN * D_DIM / 4);
  k_convert<<<2048, 256, 0, stream>>>(x_test, xte16, (long)NTEST * D_DIM / 4);
  k_transpose_bf16<<<dim3(96, 96), dim3(32, 8), 0, stream>>>(M, Mt16);
  k_copy4<<<2048, 256, 0, stream>>>((const float4*)M, (float4*)(out + 81920),
                                    (long)D_DIM * D_DIM / 4);

  k_gemm_xm<true><<<dim3(24, 128), 512, 0, stream>>>(xtr16, Mt16, x_train, sM16, s_n2);
  k_gemm_xm<false><<<dim3(24, 64), 512, 0, stream>>>(xte16, Mt16, x_test, nullptr, c_n2);

  k_gemm_cross<<<dim3(64, 128), 512, 0, stream>>>(sM16, xte16, y_train, s_n2, c_n2, part);
  k_reduce<<<32, 256, 0, stream>>>(part, out);
}

// Round 6
// 1765.889 us; speedup vs baseline: 1.2961x; 1.0569x over previous
//
#include <hip/hip_runtime.h>
#include <hip/hip_bf16.h>

#define D_DIM 3072
#define NTRAIN 16384
#define NTEST 8192

typedef __attribute__((ext_vector_type(8))) short short8;
typedef __attribute__((ext_vector_type(4))) float f32x4;

__device__ __forceinline__ unsigned short f2bf(float f) {
  union { float f; unsigned u; } x; x.f = f;
  unsigned r = x.u + 0x7FFFu + ((x.u >> 16) & 1u);
  return (unsigned short)(r >> 16);
}

__device__ __forceinline__ void gload16(const unsigned short* g, unsigned short* l) {
  __builtin_amdgcn_global_load_lds(
      (__attribute__((address_space(1))) void*)g,
      (__attribute__((address_space(3))) void*)l, 16, 0, 0);
}

// T1: bijective chunked XCD swizzle + 8x8 supertile ordering.
// Launched flat id L -> XCD gets contiguous chunk (m204 form, nwg%8==0),
// chunk traversed in 8x8 tile supertiles so the ~concurrent blocks of one
// XCD share 8 A-panels + 8 B-panels in its private L2.
// Requires gridDim.x%8==0 (or scols=gridDim.x/8 exact) and tileRows%8==0.
__device__ __forceinline__ void swz_tile(int& tileY, int& tileX) {
  const int gx = gridDim.x, gy = gridDim.y;
  const int L = blockIdx.y * gx + blockIdx.x;
  const int q = (gx * gy) >> 3;
  const int s = (L & 7) * q + (L >> 3);   // chunked per-XCD
  const int sid = s >> 6;                 // supertile id (64 tiles)
  const int t = s & 63;
  const int scols = gx >> 3;
  const int sy = sid / scols, sx = sid - sy * scols;
  tileY = sy * 8 + (t >> 3);
  tileX = sx * 8 + (t & 7);
}

// ---------------- pass 0: converts / transpose / copy ----------------
__global__ void k_convert(const float* __restrict__ in, unsigned short* __restrict__ out, long n4) {
  long i = (long)blockIdx.x * blockDim.x + threadIdx.x;
  long stride = (long)gridDim.x * blockDim.x;
  for (; i < n4; i += stride) {
    float4 v = reinterpret_cast<const float4*>(in)[i];
    ushort4 o;
    o.x = f2bf(v.x); o.y = f2bf(v.y); o.z = f2bf(v.z); o.w = f2bf(v.w);
    reinterpret_cast<ushort4*>(out)[i] = o;
  }
}

__global__ void k_copy4(const float4* __restrict__ in, float4* __restrict__ out, long n4) {
  long i = (long)blockIdx.x * blockDim.x + threadIdx.x;
  long stride = (long)gridDim.x * blockDim.x;
  for (; i < n4; i += stride) out[i] = in[i];
}

// Mt[n][k] = bf16(M[k][n])
__global__ void k_transpose_bf16(const float* __restrict__ M, unsigned short* __restrict__ Mt) {
  __shared__ float t[32][33];
  int bx = blockIdx.x * 32, by = blockIdx.y * 32;
  int tx = threadIdx.x, ty = threadIdx.y;  // 32 x 8
#pragma unroll
  for (int i = 0; i < 32; i += 8)
    t[ty + i][tx] = M[(size_t)(by + ty + i) * D_DIM + bx + tx];
  __syncthreads();
#pragma unroll
  for (int i = 0; i < 32; i += 8)
    Mt[(size_t)(bx + ty + i) * D_DIM + by + tx] = f2bf(t[tx][ty + i]);
}

// ------- 128x128 BT main loop, 512 threads (8 waves, 4M x 2N), T2 swizzle -------
__device__ __forceinline__ void mainloop512(const unsigned short* __restrict__ A,
                                            const unsigned short* __restrict__ B,
                                            int K, int rowBase, int colBase,
                                            unsigned short* As, unsigned short* Bs,
                                            f32x4 acc[2][4]) {
  const int tid = threadIdx.x;
  const int lane = tid & 63;
  const int wave = tid >> 6;                     // 0..7
  const int wm = wave >> 1, wn = wave & 1;       // 4M x 2N
  const int sr = tid >> 3;                       // staging row 0..63 (+c*64)
  const int ssl = tid & 7;                       // physical 16B slot
  const int scol = ((ssl ^ (sr & 7)) * 8);       // pre-swizzled global column
  const unsigned short* ga = A + (size_t)(rowBase + sr) * K + scol;
  const unsigned short* gb = B + (size_t)(colBase + sr) * K + scol;
  const int arow = wm * 32 + (lane & 15);
  const int brow = wn * 64 + (lane & 15);
  const int lsw = lane & 7;
  const int lhi = lane >> 4;
  for (int k0 = 0; k0 < K; k0 += 64) {
#pragma unroll
    for (int c = 0; c < 2; ++c) {
      gload16(ga + (size_t)c * 64 * K + k0, As + c * 4096 + tid * 8);
      gload16(gb + (size_t)c * 64 * K + k0, Bs + c * 4096 + tid * 8);
    }
    __syncthreads();
#pragma unroll
    for (int kk = 0; kk < 2; ++kk) {
      short8 af[2], bfr[4];
      const int sl = ((lhi + kk * 4) ^ lsw) * 8;  // swizzled read slot
#pragma unroll
      for (int i = 0; i < 2; ++i)
        af[i] = *reinterpret_cast<const short8*>(&As[(arow + i * 16) * 64 + sl]);
#pragma unroll
      for (int j = 0; j < 4; ++j)
        bfr[j] = *reinterpret_cast<const short8*>(&Bs[(brow + j * 16) * 64 + sl]);
#pragma unroll
      for (int i = 0; i < 2; ++i)
#pragma unroll
        for (int j = 0; j < 4; ++j)
          acc[i][j] = __builtin_amdgcn_mfma_f32_16x16x32_bf16(af[i], bfr[j], acc[i][j], 0, 0, 0);
    }
    __syncthreads();
  }
}

// ---------------- GEMM1: X @ M  (B = Mt). Epilogue: norm2 (+ optional sM write) ----
template <bool WRITE_SM>
__global__ __launch_bounds__(512, 4) void k_gemm_xm(const unsigned short* __restrict__ A,
                                                    const unsigned short* __restrict__ Bt,
                                                    const float* __restrict__ Xf,
                                                    unsigned short* __restrict__ smOut,
                                                    float* __restrict__ norm) {
  __shared__ unsigned short As[128 * 64], Bs[128 * 64];
  int tileY, tileX;
  swz_tile(tileY, tileX);
  const int rowBase = tileY * 128, colBase = tileX * 128;
  f32x4 acc[2][4] = {};
  mainloop512(A, Bt, D_DIM, rowBase, colBase, As, Bs, acc);
  const int tid = threadIdx.x, lane = tid & 63;
  const int wave = tid >> 6;
  const int wm = wave >> 1, wn = wave & 1;
  const int r0 = wm * 32 + (lane >> 4) * 4;
  const int c0 = colBase + wn * 64 + (lane & 15);
#pragma unroll
  for (int mi = 0; mi < 2; ++mi) {
#pragma unroll
    for (int r = 0; r < 4; ++r) {
      const size_t grow = rowBase + r0 + mi * 16 + r;
      float v = 0.f;
#pragma unroll
      for (int ni = 0; ni < 4; ++ni) {
        float a = acc[mi][ni][r];
        int gcol = c0 + ni * 16;
        v += a * Xf[grow * D_DIM + gcol];
        if (WRITE_SM) smOut[grow * D_DIM + gcol] = f2bf(a);
      }
      v += __shfl_xor(v, 1); v += __shfl_xor(v, 2);
      v += __shfl_xor(v, 4); v += __shfl_xor(v, 8);
      if ((lane & 15) == 0) atomicAdd(&norm[grow], v);
    }
  }
}

// ---------------- GEMM2: sM @ x_test^T, fused K + column-partial reduction ----
__global__ __launch_bounds__(512, 4) void k_gemm_cross(const unsigned short* __restrict__ sM,
                                                       const unsigned short* __restrict__ Xt16,
                                                       const float* __restrict__ Y,
                                                       const float* __restrict__ sn2,
                                                       const float* __restrict__ cn2,
                                                       float* __restrict__ part) {
  __shared__ unsigned short As[128 * 64], Bs[128 * 64];
  const int tid = threadIdx.x;
  int tileY, tileX;
  swz_tile(tileY, tileX);
  const int rowBase = tileY * 128, colBase = tileX * 128;
  f32x4 acc[2][4] = {};
  mainloop512(sM, Xt16, D_DIM, rowBase, colBase, As, Bs, acc);
  float* ylds = reinterpret_cast<float*>(As);                   // [128][12] padded
  float* snlds = ylds + 128 * 12;                               // [128]
  float (*pcol)[11] = reinterpret_cast<float(*)[11]>(Bs);       // [128][11]
  for (int i = tid; i < 1280; i += 512)
    ylds[(i / 10) * 12 + (i % 10)] = Y[(size_t)rowBase * 10 + i];
  if (tid < 128) snlds[tid] = sn2[rowBase + tid];
  for (int i = tid; i < 128 * 11; i += 512) (&pcol[0][0])[i] = 0.f;
  __syncthreads();
  const int lane = tid & 63;
  const int wave = tid >> 6;
  const int wm = wave >> 1, wn = wave & 1;
  const int r0 = wm * 32 + (lane >> 4) * 4;
  const int c0l = wn * 64 + (lane & 15);
#pragma unroll
  for (int ni = 0; ni < 4; ++ni) {
    const float cnv = cn2[colBase + c0l + ni * 16];
    float ps[11];
#pragma unroll
    for (int c = 0; c < 11; ++c) ps[c] = 0.f;
#pragma unroll
    for (int mi = 0; mi < 2; ++mi) {
#pragma unroll
      for (int r = 0; r < 4; ++r) {
        const int lrow = r0 + mi * 16 + r;
        float d2 = snlds[lrow] + cnv - 2.f * acc[mi][ni][r];
        float kv = exp2f(-0.14426950408889634f * sqrtf(fmaxf(d2, 0.f)));
        ps[10] += kv;
        f32x4 y0 = *reinterpret_cast<const f32x4*>(&ylds[lrow * 12]);
        f32x4 y1 = *reinterpret_cast<const f32x4*>(&ylds[lrow * 12 + 4]);
        float2 y2 = *reinterpret_cast<const float2*>(&ylds[lrow * 12 + 8]);
#pragma unroll
        for (int c = 0; c < 4; ++c) ps[c] += kv * y0[c];
#pragma unroll
        for (int c = 0; c < 4; ++c) ps[4 + c] += kv * y1[c];
        ps[8] += kv * y2.x;
        ps[9] += kv * y2.y;
      }
    }
#pragma unroll
    for (int c = 0; c < 11; ++c) {
      float v = ps[c];
      v += __shfl_xor(v, 16);
      v += __shfl_xor(v, 32);
      if (lane < 16) atomicAdd(&pcol[wn * 64 + ni * 16 + lane][c], v);
    }
  }
  __syncthreads();
  if (tid < 128) {
    int gcol = colBase + tid;
#pragma unroll
    for (int c = 0; c < 11; ++c)
      part[((size_t)tileY * 11 + c) * NTEST + gcol] = pcol[tid][c];
  }
}

// ---------------- final reduce: out[t,c] = num/den ----------------
__global__ void k_reduce(const float* __restrict__ part, float* __restrict__ out) {
  int t = blockIdx.x * blockDim.x + threadIdx.x;  // 8192 threads
  float num[10] = {0, 0, 0, 0, 0, 0, 0, 0, 0, 0};
  float den = 0.f;
  for (int it = 0; it < NTRAIN / 128; ++it) {
    const float* p = part + (size_t)it * 11 * NTEST + t;
#pragma unroll
    for (int c = 0; c < 10; ++c) num[c] += p[(size_t)c * NTEST];
    den += p[(size_t)10 * NTEST];
  }
  float inv = 1.f / den;
#pragma unroll
  for (int c = 0; c < 10; ++c) out[(size_t)t * 10 + c] = num[c] * inv;
}

extern "C" void kernel_launch(void* const* d_in, const int* in_sizes, int n_in,
                              void* d_out, int out_size, void* d_ws, size_t ws_size,
                              hipStream_t stream) {
  const float* x_train = (const float*)d_in[0];
  const float* y_train = (const float*)d_in[1];
  const float* x_test  = (const float*)d_in[2];
  const float* M       = (const float*)d_in[3];
  float* out = (float*)d_out;

  char* ws = (char*)d_ws;
  unsigned short* xtr16 = (unsigned short*)(ws + 0);          // 16384*3072*2 = 100663296
  unsigned short* xte16 = (unsigned short*)(ws + 100663296);  // 8192*3072*2  = 50331648
  unsigned short* Mt16  = (unsigned short*)(ws + 150994944);  // 3072*3072*2  = 18874368
  unsigned short* sM16  = (unsigned short*)(ws + 169869312);  // 16384*3072*2 = 100663296
  float* s_n2 = (float*)(ws + 270532608);                     // 65536
  float* c_n2 = (float*)(ws + 270598144);                     // 32768
  float* part = (float*)(ws + 270630912);                     // 128*11*8192*4 = 46137344

  hipMemsetAsync(ws + 270532608, 0, 98304, stream);  // s_n2 + c_n2

  k_convert<<<2048, 256, 0, stream>>>(x_train, xtr16, (long)NTRAIN * D_DIM / 4);
  k_convert<<<2048, 256, 0, stream>>>(x_test, xte16, (long)NTEST * D_DIM / 4);
  k_transpose_bf16<<<dim3(96, 96), dim3(32, 8), 0, stream>>>(M, Mt16);
  k_copy4<<<2048, 256, 0, stream>>>((const float4*)M, (float4*)(out + 81920),
                                    (long)D_DIM * D_DIM / 4);

  k_gemm_xm<true><<<dim3(24, 128), 512, 0, stream>>>(xtr16, Mt16, x_train, sM16, s_n2);
  k_gemm_xm<false><<<dim3(24, 64), 512, 0, stream>>>(xte16, Mt16, x_test, nullptr, c_n2);

  k_gemm_cross<<<dim3(64, 128), 512, 0, stream>>>(sM16, xte16, y_train, s_n2, c_n2, part);
  k_reduce<<<32, 256, 0, stream>>>(part, out);
}